// Round 4
// baseline (842.438 us; speedup 1.0000x reference)
//
#include <hip/hip_runtime.h>

typedef short bf16x8 __attribute__((ext_vector_type(8)));
typedef float f32x4  __attribute__((ext_vector_type(4)));

#define AS1 __attribute__((address_space(1)))
#define AS3 __attribute__((address_space(3)))

__device__ __forceinline__ void gload16(const void* g, void* l) {
  __builtin_amdgcn_global_load_lds((const AS1 void*)g, (AS3 void*)l, 16, 0, 0);
}

__device__ __forceinline__ short f2bf(float f) {
  union { float fv; unsigned u; } v; v.fv = f;
  unsigned r = v.u + 0x7fffu + ((v.u >> 16) & 1u);
  return (short)(r >> 16);
}

// max across the 16 lanes of a DPP row (our q-row group) in 4 VALU instrs
__device__ __forceinline__ float dppmax16(float x) {
  int t;
  t = __builtin_amdgcn_update_dpp(0, __float_as_int(x), 0xB1, 0xf, 0xf, false);  // quad_perm(1,0,3,2)
  x = fmaxf(x, __int_as_float(t));
  t = __builtin_amdgcn_update_dpp(0, __float_as_int(x), 0x4E, 0xf, 0xf, false);  // quad_perm(2,3,0,1)
  x = fmaxf(x, __int_as_float(t));
  t = __builtin_amdgcn_update_dpp(0, __float_as_int(x), 0x124, 0xf, 0xf, false); // row_ror:4
  x = fmaxf(x, __int_as_float(t));
  t = __builtin_amdgcn_update_dpp(0, __float_as_int(x), 0x128, 0xf, 0xf, false); // row_ror:8
  x = fmaxf(x, __int_as_float(t));
  return x;
}

// ---------------- cast x (fp32 -> bf16), 4 elems/thread ----------------
__global__ void cast_x_kernel(const float* __restrict__ x, short* __restrict__ xb, long n4) {
  long i = (long)blockIdx.x * 256 + threadIdx.x;
  if (i < n4) {
    float4 v = ((const float4*)x)[i];
    short4 s;
    s.x = f2bf(v.x); s.y = f2bf(v.y); s.z = f2bf(v.z); s.w = f2bf(v.w);
    ((short4*)xb)[i] = s;
  }
}

// ---------------- weight prep ----------------
__global__ void prep_kernel(const float* __restrict__ left_w, const float* __restrict__ diag,
                            const float* __restrict__ right_w,
                            short* __restrict__ LT, short* __restrict__ WT) {
  long idx = (long)blockIdx.x * 256 + threadIdx.x;
  const long LTN = 4L * 128 * 2048;
  const long WTN = 4L * 16 * 128 * 256;
  if (idx < LTN) {
    LT[idx] = f2bf(left_w[idx]);
  } else if (idx < LTN + WTN) {
    long j = idx - LTN;
    int d = (int)(j & 255);
    long rest = j >> 8;
    int e = (int)(rest & 127);
    long gi = rest >> 7;
    int i = (int)(gi >> 4), n = (int)(gi & 15);
    float v;
    if (d < 128) v = diag[(gi * 128 + d) * 128 + e];
    else         v = right_w[((long)i * 2048 + n * 128 + e) * 128 + (d - 128)];
    WT[j] = f2bf(v);
  }
}

// ---------------- 128x128-tile GEMM (XOR-swizzled LDS): C = A @ BT^T ----------------
__global__ __launch_bounds__(256) void gemm_bt(const short* __restrict__ A, const short* __restrict__ BT,
                                               short* __restrict__ C, int M, int N, int K) {
  __shared__ __align__(16) short As[128 * 64];
  __shared__ __align__(16) short Bs[128 * 64];
  int tid = threadIdx.x, w = tid >> 6, lane = tid & 63;
  int m0 = blockIdx.x * 128, n0 = blockIdx.y * 128;
  int wm = (w >> 1) * 64, wn = (w & 1) * 64;
  int quad = lane >> 4, l16 = lane & 15;
  int srow = lane >> 3;
  int schunk = ((lane & 7) ^ srow) * 8;   // XOR-swizzled source chunk
  f32x4 acc[4][4] = {};
  for (int k0 = 0; k0 < K; k0 += 64) {
    for (int p = 0; p < 4; ++p) {
      int r = p * 32 + w * 8 + srow;
      gload16(&A[(long)(m0 + r) * K + k0 + schunk], &As[(p * 32 + w * 8) * 64]);
      gload16(&BT[(long)(n0 + r) * K + k0 + schunk], &Bs[(p * 32 + w * 8) * 64]);
    }
    __syncthreads();
#pragma unroll
    for (int kk = 0; kk < 2; ++kk) {
      int c = (((kk * 4 + quad) ^ (l16 & 7)) * 8);
      bf16x8 a[4], b[4];
#pragma unroll
      for (int t = 0; t < 4; ++t) a[t] = *(const bf16x8*)&As[(wm + t * 16 + l16) * 64 + c];
#pragma unroll
      for (int t = 0; t < 4; ++t) b[t] = *(const bf16x8*)&Bs[(wn + t * 16 + l16) * 64 + c];
#pragma unroll
      for (int mt = 0; mt < 4; ++mt)
#pragma unroll
        for (int nt = 0; nt < 4; ++nt)
          acc[mt][nt] = __builtin_amdgcn_mfma_f32_16x16x32_bf16(a[mt], b[nt], acc[mt][nt], 0, 0, 0);
    }
    __syncthreads();
  }
#pragma unroll
  for (int mt = 0; mt < 4; ++mt)
#pragma unroll
    for (int nt = 0; nt < 4; ++nt)
#pragma unroll
      for (int r = 0; r < 4; ++r) {
        int m = m0 + wm + mt * 16 + quad * 4 + r;
        int n = n0 + wn + nt * 16 + l16;
        C[(long)m * N + n] = f2bf(acc[mt][nt][r]);
      }
}

// ---------------- grouped lori GEMM (XOR-swizzled LDS) ----------------
__global__ __launch_bounds__(256) void lori_gemm(const short* __restrict__ tok, const short* __restrict__ rnk,
                                                 int rstride, const short* __restrict__ WT,
                                                 const float* __restrict__ rb, const float* __restrict__ bp,
                                                 int i_base, short* __restrict__ qb, short* __restrict__ kb,
                                                 short* __restrict__ vT, float* __restrict__ out) {
  __shared__ __align__(16) short As[128 * 64];
  __shared__ __align__(16) short Bs[128 * 64];
  int tid = threadIdx.x, w = tid >> 6, lane = tid & 63;
  int i = i_base + (blockIdx.y >> 4);
  int n = blockIdx.y & 15;
  int t0 = blockIdx.x * 128;
  int co = (i < 3) ? i * 128 : 0;
  const short* WTn = WT + (long)(i * 16 + n) * 128 * 256;
  int wm = (w >> 1) * 64, wn = (w & 1) * 64;
  int quad = lane >> 4, l16 = lane & 15;
  int srow = lane >> 3;
  int schunk = ((lane & 7) ^ srow) * 8;
  f32x4 acc[4][4] = {};
#pragma unroll
  for (int kt = 0; kt < 4; ++kt) {
    for (int p = 0; p < 4; ++p) {
      int r = p * 32 + w * 8 + srow;
      const short* ga;
      if (kt < 2) ga = &tok[(long)(t0 + r) * 2048 + n * 128 + kt * 64 + schunk];
      else        ga = &rnk[(long)(t0 + r) * rstride + co + (kt - 2) * 64 + schunk];
      gload16(ga, &As[(p * 32 + w * 8) * 64]);
      gload16(&WTn[r * 256 + kt * 64 + schunk], &Bs[(p * 32 + w * 8) * 64]);
    }
    __syncthreads();
#pragma unroll
    for (int kk = 0; kk < 2; ++kk) {
      int c = (((kk * 4 + quad) ^ (l16 & 7)) * 8);
      bf16x8 a[4], b[4];
#pragma unroll
      for (int t = 0; t < 4; ++t) a[t] = *(const bf16x8*)&As[(wm + t * 16 + l16) * 64 + c];
#pragma unroll
      for (int t = 0; t < 4; ++t) b[t] = *(const bf16x8*)&Bs[(wn + t * 16 + l16) * 64 + c];
#pragma unroll
      for (int mt = 0; mt < 4; ++mt)
#pragma unroll
        for (int nt = 0; nt < 4; ++nt)
          acc[mt][nt] = __builtin_amdgcn_mfma_f32_16x16x32_bf16(a[mt], b[nt], acc[mt][nt], 0, 0, 0);
    }
    __syncthreads();
  }
  int b = t0 >> 11;
  int tl0 = t0 & 2047;
  const float QSC = 0.08838834764831845f * 1.4426950408889634f;  // 1/sqrt(128) * log2(e)
#pragma unroll
  for (int mt = 0; mt < 4; ++mt) {
#pragma unroll
    for (int nt = 0; nt < 4; ++nt) {
      int e = wn + nt * 16 + l16;
      int c = n * 128 + e;
      float bias = rb[i * 2048 + c] + bp[i * 2048 + c];
      int tl = tl0 + wm + mt * 16 + quad * 4;
      if (i == 0) {
#pragma unroll
        for (int r = 0; r < 4; ++r)
          qb[((long)(b * 16 + n) * 2048 + tl + r) * 128 + e] = f2bf((acc[mt][nt][r] + bias) * QSC);
      } else if (i == 1) {
#pragma unroll
        for (int r = 0; r < 4; ++r)
          kb[((long)(b * 16 + n) * 2048 + tl + r) * 128 + e] = f2bf(acc[mt][nt][r] + bias);
      } else if (i == 2) {
        short4 s4;
        s4.x = f2bf(acc[mt][nt][0] + bias);
        s4.y = f2bf(acc[mt][nt][1] + bias);
        s4.z = f2bf(acc[mt][nt][2] + bias);
        s4.w = f2bf(acc[mt][nt][3] + bias);
        *(short4*)&vT[((long)(b * 16 + n) * 128 + e) * 2048 + tl] = s4;
      } else {
#pragma unroll
        for (int r = 0; r < 4; ++r)
          out[(long)(t0 + wm + mt * 16 + quad * 4 + r) * 2048 + c] = acc[mt][nt][r] + bias;
      }
    }
  }
}

// ---------------- flash attention v4: barrier-free, K/V fragments direct global->VGPR ----------------
// qb,kb: [bh][t][d] bf16 (q pre-scaled by log2e/sqrt(128)); vT: [bh][d][t]; y: [b][t][h*128+d]
// grid: 1024 blocks 1D; id&7 spreads over XCDs; all q-tiles of a bh share one XCD's L2.
__global__ __launch_bounds__(256) void attn_kernel(const short* __restrict__ qb, const short* __restrict__ kb,
                                                   const short* __restrict__ vT, short* __restrict__ y) {
  __shared__ __align__(16) short ps[4][32 * 64];    // P per wave, 8-chunk XOR swizzle per row
  int tid = threadIdx.x, w = tid >> 6, lane = tid & 63;
  int id = blockIdx.x;
  int xcd = id & 7, slot = id >> 3;
  int qt = 15 - (slot & 15);          // long q-tiles first
  int bh = xcd + 8 * (slot >> 4);     // 8 bh per XCD, q-tiles of one bh co-resident
  int b = bh >> 4, h = bh & 15;
  int quad = lane >> 4, l16 = lane & 15;

  // Q fragments direct global->VGPR (A-layout): rows w*32 + mt*16 + l16
  bf16x8 aq[2][4];
#pragma unroll
  for (int mt = 0; mt < 2; ++mt)
#pragma unroll
    for (int kk = 0; kk < 4; ++kk)
      aq[mt][kk] = *(const bf16x8*)&qb[((long)bh * 2048 + qt * 128 + w * 32 + mt * 16 + l16) * 128 + kk * 32 + quad * 8];

  f32x4 O[2][8] = {};
  f32x4 Lacc[2] = {};
  f32x4 mst[2];
#pragma unroll
  for (int mt = 0; mt < 2; ++mt) mst[mt] = f32x4{-3.0e38f, -3.0e38f, -3.0e38f, -3.0e38f};
  const bf16x8 ones = {(short)0x3F80, (short)0x3F80, (short)0x3F80, (short)0x3F80,
                       (short)0x3F80, (short)0x3F80, (short)0x3F80, (short)0x3F80};
  short* psw = &ps[w][0];

  const short* kbase = kb + (long)bh * 2048 * 128 + l16 * 128 + quad * 8;  // + key*128 + kk*32
  const short* vbase = vT + (long)bh * 128 * 2048 + l16 * 2048 + quad * 8; // + d16*16*2048 + key0 + kk*32

  // wave's own last key-tile: rows [qt*128 + w*32, +31] need keys <= qt*128 + w*32 + 31
  int jmax = 2 * qt + (w >> 1);
  for (int jt = 0; jt <= jmax; ++jt) {
    // S = Q @ K^T  (wave: 32 rows x 64 keys), K fragments straight from L2
    f32x4 s[2][4] = {};
#pragma unroll
    for (int nt = 0; nt < 4; ++nt)
#pragma unroll
      for (int kk = 0; kk < 4; ++kk) {
        bf16x8 bk = *(const bf16x8*)&kbase[(long)(jt * 64 + nt * 16) * 128 + kk * 32];
        s[0][nt] = __builtin_amdgcn_mfma_f32_16x16x32_bf16(aq[0][kk], bk, s[0][nt], 0, 0, 0);
        s[1][nt] = __builtin_amdgcn_mfma_f32_16x16x32_bf16(aq[1][kk], bk, s[1][nt], 0, 0, 0);
      }
    if (jt == jmax) {
#pragma unroll
      for (int mt = 0; mt < 2; ++mt)
#pragma unroll
        for (int nt = 0; nt < 4; ++nt) {
          int key = jt * 64 + nt * 16 + l16;
#pragma unroll
          for (int r = 0; r < 4; ++r) {
            int rowg = qt * 128 + w * 32 + mt * 16 + quad * 4 + r;
            if (key > rowg) s[mt][nt][r] = -3.0e38f;
          }
        }
    }
#pragma unroll
    for (int mt = 0; mt < 2; ++mt) {
      // running max + rescale factor (base-2 domain); DPP 16-lane reduce
      f32x4 alv;
#pragma unroll
      for (int r = 0; r < 4; ++r) {
        float mx = fmaxf(fmaxf(s[mt][0][r], s[mt][1][r]), fmaxf(s[mt][2][r], s[mt][3][r]));
        mx = dppmax16(mx);
        float nm = fmaxf(mst[mt][r], mx);
        alv[r] = __builtin_amdgcn_exp2f(mst[mt][r] - nm);
        mst[mt][r] = nm;
      }
      Lacc[mt] *= alv;
#pragma unroll
      for (int dt = 0; dt < 8; ++dt) O[mt][dt] *= alv;
      // P = exp2(S - m), write to swizzled LDS (C-layout -> A-layout), per-wave region
#pragma unroll
      for (int nt = 0; nt < 4; ++nt)
#pragma unroll
        for (int r = 0; r < 4; ++r) {
          float p = __builtin_amdgcn_exp2f(s[mt][nt][r] - mst[mt][r]);
          int row = mt * 16 + quad * 4 + r;
          int cw = (nt * 2 + (l16 >> 3)) ^ (row & 7);
          psw[row * 64 + cw * 8 + (l16 & 7)] = f2bf(p);
        }
      // O += P @ V ; Lacc += P @ 1  (V fragments straight from L2)
#pragma unroll
      for (int kk = 0; kk < 2; ++kk) {
        bf16x8 ap = *(const bf16x8*)&psw[(mt * 16 + l16) * 64 + (((kk * 4 + quad) ^ (l16 & 7)) * 8)];
#pragma unroll
        for (int dt = 0; dt < 8; ++dt) {
          bf16x8 bv = *(const bf16x8*)&vbase[(long)(dt * 16) * 2048 + jt * 64 + kk * 32];
          O[mt][dt] = __builtin_amdgcn_mfma_f32_16x16x32_bf16(ap, bv, O[mt][dt], 0, 0, 0);
        }
        Lacc[mt] = __builtin_amdgcn_mfma_f32_16x16x32_bf16(ap, ones, Lacc[mt], 0, 0, 0);
      }
    }
  }
  // epilogue: y = O / l
#pragma unroll
  for (int mt = 0; mt < 2; ++mt) {
    f32x4 inv;
#pragma unroll
    for (int r = 0; r < 4; ++r) inv[r] = __builtin_amdgcn_rcpf(Lacc[mt][r]);
#pragma unroll
    for (int dt = 0; dt < 8; ++dt)
#pragma unroll
      for (int r = 0; r < 4; ++r) {
        int t = qt * 128 + w * 32 + mt * 16 + quad * 4 + r;
        y[((long)(b * 2048 + t)) * 2048 + h * 128 + dt * 16 + l16] = f2bf(O[mt][dt][r] * inv[r]);
      }
  }
}

extern "C" void kernel_launch(void* const* d_in, const int* in_sizes, int n_in,
                              void* d_out, int out_size, void* d_ws, size_t ws_size,
                              hipStream_t stream) {
  const float* x       = (const float*)d_in[0];
  const float* diag    = (const float*)d_in[1];
  const float* left_w  = (const float*)d_in[2];
  const float* right_w = (const float*)d_in[3];
  const float* right_b = (const float*)d_in[4];
  const float* bias_p  = (const float*)d_in[5];
  float* out = (float*)d_out;

  char* ws = (char*)d_ws;
  short* xb = (short*)(ws + 0);              // 33,554,432 B  (aliased as y after attention)
  short* LT = (short*)(ws + 33554432);       //  2,097,152 B
  short* WT = (short*)(ws + 35651584);       //  4,194,304 B
  short* xl = (short*)(ws + 39845888);       //  6,291,456 B
  short* yl = (short*)(ws + 46137344);       //  2,097,152 B
  short* qb = (short*)(ws + 48234496);       // 33,554,432 B
  short* kb = (short*)(ws + 81788928);       // 33,554,432 B
  short* vT = (short*)(ws + 115343360);      // 33,554,432 B
  short* y  = xb;

  cast_x_kernel<<<16384, 256, 0, stream>>>(x, xb, 4194304L);
  prep_kernel<<<12288, 256, 0, stream>>>(left_w, diag, right_w, LT, WT);
  gemm_bt<<<dim3(64, 3), 256, 0, stream>>>(xb, LT, xl, 8192, 384, 2048);
  lori_gemm<<<dim3(64, 48), 256, 0, stream>>>(xb, xl, 384, WT, right_b, bias_p, 0, qb, kb, vT, nullptr);
  attn_kernel<<<dim3(1024), 256, 0, stream>>>(qb, kb, vT, y);
  gemm_bt<<<dim3(64, 1), 256, 0, stream>>>(y, LT + 3L * 128 * 2048, yl, 8192, 128, 2048);
  lori_gemm<<<dim3(64, 16), 256, 0, stream>>>(y, yl, 128, WT, right_b, bias_p, 3, nullptr, nullptr, nullptr, out);
}

// Round 5
// 514.714 us; speedup vs baseline: 1.6367x; 1.6367x over previous
//
#include <hip/hip_runtime.h>

typedef short bf16x8 __attribute__((ext_vector_type(8)));
typedef short bf16x4 __attribute__((ext_vector_type(4)));
typedef float f32x4  __attribute__((ext_vector_type(4)));

#define AS1 __attribute__((address_space(1)))
#define AS3 __attribute__((address_space(3)))

__device__ __forceinline__ void gload16(const void* g, void* l) {
  __builtin_amdgcn_global_load_lds((const AS1 void*)g, (AS3 void*)l, 16, 0, 0);
}

__device__ __forceinline__ short f2bf(float f) {
  union { float fv; unsigned u; } v; v.fv = f;
  unsigned r = v.u + 0x7fffu + ((v.u >> 16) & 1u);
  return (short)(r >> 16);
}

// ---------------- cast x (fp32 -> bf16), 4 elems/thread ----------------
__global__ void cast_x_kernel(const float* __restrict__ x, short* __restrict__ xb, long n4) {
  long i = (long)blockIdx.x * 256 + threadIdx.x;
  if (i < n4) {
    float4 v = ((const float4*)x)[i];
    short4 s;
    s.x = f2bf(v.x); s.y = f2bf(v.y); s.z = f2bf(v.z); s.w = f2bf(v.w);
    ((short4*)xb)[i] = s;
  }
}

// ---------------- weight prep ----------------
__global__ void prep_kernel(const float* __restrict__ left_w, const float* __restrict__ diag,
                            const float* __restrict__ right_w,
                            short* __restrict__ LT, short* __restrict__ WT) {
  long idx = (long)blockIdx.x * 256 + threadIdx.x;
  const long LTN = 4L * 128 * 2048;
  const long WTN = 4L * 16 * 128 * 256;
  if (idx < LTN) {
    LT[idx] = f2bf(left_w[idx]);
  } else if (idx < LTN + WTN) {
    long j = idx - LTN;
    int d = (int)(j & 255);
    long rest = j >> 8;
    int e = (int)(rest & 127);
    long gi = rest >> 7;
    int i = (int)(gi >> 4), n = (int)(gi & 15);
    float v;
    if (d < 128) v = diag[(gi * 128 + d) * 128 + e];
    else         v = right_w[((long)i * 2048 + n * 128 + e) * 128 + (d - 128)];
    WT[j] = f2bf(v);
  }
}

// ---------------- 128x128-tile GEMM (XOR-swizzled LDS): C = A @ BT^T ----------------
__global__ __launch_bounds__(256) void gemm_bt(const short* __restrict__ A, const short* __restrict__ BT,
                                               short* __restrict__ C, int M, int N, int K) {
  __shared__ __align__(16) short As[128 * 64];
  __shared__ __align__(16) short Bs[128 * 64];
  int tid = threadIdx.x, w = tid >> 6, lane = tid & 63;
  int m0 = blockIdx.x * 128, n0 = blockIdx.y * 128;
  int wm = (w >> 1) * 64, wn = (w & 1) * 64;
  int quad = lane >> 4, l16 = lane & 15;
  int srow = lane >> 3;
  int schunk = ((lane & 7) ^ srow) * 8;   // XOR-swizzled source chunk
  f32x4 acc[4][4] = {};
  for (int k0 = 0; k0 < K; k0 += 64) {
    for (int p = 0; p < 4; ++p) {
      int r = p * 32 + w * 8 + srow;
      gload16(&A[(long)(m0 + r) * K + k0 + schunk], &As[(p * 32 + w * 8) * 64]);
      gload16(&BT[(long)(n0 + r) * K + k0 + schunk], &Bs[(p * 32 + w * 8) * 64]);
    }
    __syncthreads();
#pragma unroll
    for (int kk = 0; kk < 2; ++kk) {
      int c = (((kk * 4 + quad) ^ (l16 & 7)) * 8);
      bf16x8 a[4], b[4];
#pragma unroll
      for (int t = 0; t < 4; ++t) a[t] = *(const bf16x8*)&As[(wm + t * 16 + l16) * 64 + c];
#pragma unroll
      for (int t = 0; t < 4; ++t) b[t] = *(const bf16x8*)&Bs[(wn + t * 16 + l16) * 64 + c];
#pragma unroll
      for (int mt = 0; mt < 4; ++mt)
#pragma unroll
        for (int nt = 0; nt < 4; ++nt)
          acc[mt][nt] = __builtin_amdgcn_mfma_f32_16x16x32_bf16(a[mt], b[nt], acc[mt][nt], 0, 0, 0);
    }
    __syncthreads();
  }
#pragma unroll
  for (int mt = 0; mt < 4; ++mt)
#pragma unroll
    for (int nt = 0; nt < 4; ++nt)
#pragma unroll
      for (int r = 0; r < 4; ++r) {
        int m = m0 + wm + mt * 16 + quad * 4 + r;
        int n = n0 + wn + nt * 16 + l16;
        C[(long)m * N + n] = f2bf(acc[mt][nt][r]);
      }
}

// ---------------- grouped lori GEMM (XOR-swizzled LDS) ----------------
__global__ __launch_bounds__(256) void lori_gemm(const short* __restrict__ tok, const short* __restrict__ rnk,
                                                 int rstride, const short* __restrict__ WT,
                                                 const float* __restrict__ rb, const float* __restrict__ bp,
                                                 int i_base, short* __restrict__ qb, short* __restrict__ kb,
                                                 short* __restrict__ vT, float* __restrict__ out) {
  __shared__ __align__(16) short As[128 * 64];
  __shared__ __align__(16) short Bs[128 * 64];
  int tid = threadIdx.x, w = tid >> 6, lane = tid & 63;
  int i = i_base + (blockIdx.y >> 4);
  int n = blockIdx.y & 15;
  int t0 = blockIdx.x * 128;
  int co = (i < 3) ? i * 128 : 0;
  const short* WTn = WT + (long)(i * 16 + n) * 128 * 256;
  int wm = (w >> 1) * 64, wn = (w & 1) * 64;
  int quad = lane >> 4, l16 = lane & 15;
  int srow = lane >> 3;
  int schunk = ((lane & 7) ^ srow) * 8;
  f32x4 acc[4][4] = {};
#pragma unroll
  for (int kt = 0; kt < 4; ++kt) {
    for (int p = 0; p < 4; ++p) {
      int r = p * 32 + w * 8 + srow;
      const short* ga;
      if (kt < 2) ga = &tok[(long)(t0 + r) * 2048 + n * 128 + kt * 64 + schunk];
      else        ga = &rnk[(long)(t0 + r) * rstride + co + (kt - 2) * 64 + schunk];
      gload16(ga, &As[(p * 32 + w * 8) * 64]);
      gload16(&WTn[r * 256 + kt * 64 + schunk], &Bs[(p * 32 + w * 8) * 64]);
    }
    __syncthreads();
#pragma unroll
    for (int kk = 0; kk < 2; ++kk) {
      int c = (((kk * 4 + quad) ^ (l16 & 7)) * 8);
      bf16x8 a[4], b[4];
#pragma unroll
      for (int t = 0; t < 4; ++t) a[t] = *(const bf16x8*)&As[(wm + t * 16 + l16) * 64 + c];
#pragma unroll
      for (int t = 0; t < 4; ++t) b[t] = *(const bf16x8*)&Bs[(wn + t * 16 + l16) * 64 + c];
#pragma unroll
      for (int mt = 0; mt < 4; ++mt)
#pragma unroll
        for (int nt = 0; nt < 4; ++nt)
          acc[mt][nt] = __builtin_amdgcn_mfma_f32_16x16x32_bf16(a[mt], b[nt], acc[mt][nt], 0, 0, 0);
    }
    __syncthreads();
  }
  int b = t0 >> 11;
  int tl0 = t0 & 2047;
  const float QSC = 0.08838834764831845f * 1.4426950408889634f;  // 1/sqrt(128) * log2(e)
#pragma unroll
  for (int mt = 0; mt < 4; ++mt) {
#pragma unroll
    for (int nt = 0; nt < 4; ++nt) {
      int e = wn + nt * 16 + l16;
      int c = n * 128 + e;
      float bias = rb[i * 2048 + c] + bp[i * 2048 + c];
      int tl = tl0 + wm + mt * 16 + quad * 4;
      if (i == 0) {
#pragma unroll
        for (int r = 0; r < 4; ++r)
          qb[((long)(b * 16 + n) * 2048 + tl + r) * 128 + e] = f2bf((acc[mt][nt][r] + bias) * QSC);
      } else if (i == 1) {
#pragma unroll
        for (int r = 0; r < 4; ++r)
          kb[((long)(b * 16 + n) * 2048 + tl + r) * 128 + e] = f2bf(acc[mt][nt][r] + bias);
      } else if (i == 2) {
        short4 s4;
        s4.x = f2bf(acc[mt][nt][0] + bias);
        s4.y = f2bf(acc[mt][nt][1] + bias);
        s4.z = f2bf(acc[mt][nt][2] + bias);
        s4.w = f2bf(acc[mt][nt][3] + bias);
        *(short4*)&vT[((long)(b * 16 + n) * 128 + e) * 2048 + tl] = s4;
      } else {
#pragma unroll
        for (int r = 0; r < 4; ++r)
          out[(long)(t0 + wm + mt * 16 + quad * 4 + r) * 2048 + c] = acc[mt][nt][r] + bias;
      }
    }
  }
}

// ---------------- flash attention v5: S^T trick — P stays in registers (no LDS round-trip) ----------------
// S^T = K·Q^T via 16x16x32 (same fragments as r3, operands swapped). S^T C-layout == B-fragment
// layout of mfma_f32_16x16x16_bf16, so PV runs as O^T = V^T·P^T with P direct from registers.
// qb,kb: [bh][t][d] bf16 (q pre-scaled by log2e/sqrt(128)); vT: [bh][d][t]; y: [b][t][h*128+d]
__global__ __launch_bounds__(256) void attn_kernel(const short* __restrict__ qb, const short* __restrict__ kb,
                                                   const short* __restrict__ vT, short* __restrict__ y) {
  __shared__ __align__(16) short ks[2][64 * 128];   // K tiles, 16-chunk XOR swizzle per row
  __shared__ __align__(16) short vs[2][128 * 64];   // V^T tiles, 8-chunk XOR swizzle per row
  int tid = threadIdx.x, w = tid >> 6, lane = tid & 63;
  int id = blockIdx.x;
  int xcd = id & 7, slot = id >> 3;
  int qt = 15 - (slot & 15);          // long q-tiles first
  int bh = xcd + 8 * (slot >> 4);     // 8 bh per XCD, q-tiles of one bh co-resident
  int b = bh >> 4, h = bh & 15;
  int quad = lane >> 4, l16 = lane & 15;

  // Q fragments global->VGPR; serve as B-operand (k=d=quad*8+j, n=q=l16) of S^T MFMA
  bf16x8 aq[2][4];
#pragma unroll
  for (int mt = 0; mt < 2; ++mt)
#pragma unroll
    for (int kk = 0; kk < 4; ++kk)
      aq[mt][kk] = *(const bf16x8*)&qb[((long)bh * 2048 + qt * 128 + w * 32 + mt * 16 + l16) * 128 + kk * 32 + quad * 8];

  f32x4 O[2][8] = {};                 // O^T tiles: row=d (quad*4+r within dt), col=q (l16)
  f32x4 Lacc[2] = {};                 // ones-MFMA row-sum accumulator (rows identical)
  float mst[2] = {-3.0e38f, -3.0e38f};
  const bf16x4 ones4 = {(short)0x3F80, (short)0x3F80, (short)0x3F80, (short)0x3F80};

  // staging lane constants (same as r3)
  int kq = lane >> 4;
  int kchunk = l16 ^ (w * 4 + kq);
  int vrow8 = lane >> 3;
  int vchunk = (lane & 7) ^ vrow8;

  const short* kbase = kb + (long)bh * 2048 * 128;
  const short* vbase = vT + (long)bh * 128 * 2048;

#define STAGE(JT, BUF) {                                                              \
    for (int p = 0; p < 4; ++p) {                                                     \
      int r = p * 16 + w * 4 + kq;                                                    \
      gload16(&kbase[((long)((JT) * 64 + r)) * 128 + kchunk * 8], &ks[BUF][(p * 16 + w * 4) * 128]); \
      int r2 = p * 32 + w * 8 + vrow8;                                                \
      gload16(&vbase[(long)r2 * 2048 + (JT) * 64 + vchunk * 8], &vs[BUF][(p * 32 + w * 8) * 64]);    \
    }                                                                                 \
  }

  int jmax = 2 * qt + 1;
  STAGE(0, 0)
  __syncthreads();
  for (int jt = 0; jt <= jmax; ++jt) {
    int cur = jt & 1;
    if (jt < jmax) STAGE(jt + 1, cur ^ 1)   // prefetch overlaps compute below

    bool active = !(jt == jmax && w < 2);   // waves 0,1 fully masked on the last diagonal sub-tile
    if (active) {
      // S^T = K·Q^T  (wave: 64 keys x 32 q)
      f32x4 s[2][4] = {};
#pragma unroll
      for (int nt = 0; nt < 4; ++nt)
#pragma unroll
        for (int kk = 0; kk < 4; ++kk) {
          bf16x8 bk = *(const bf16x8*)&ks[cur][(nt * 16 + l16) * 128 + (((kk * 4 + quad) ^ l16) * 8)];
          s[0][nt] = __builtin_amdgcn_mfma_f32_16x16x32_bf16(bk, aq[0][kk], s[0][nt], 0, 0, 0);
          s[1][nt] = __builtin_amdgcn_mfma_f32_16x16x32_bf16(bk, aq[1][kk], s[1][nt], 0, 0, 0);
        }
      if (jt >= 2 * qt) {
#pragma unroll
        for (int mt = 0; mt < 2; ++mt)
#pragma unroll
          for (int nt = 0; nt < 4; ++nt) {
            int q = qt * 128 + w * 32 + mt * 16 + l16;
#pragma unroll
            for (int r = 0; r < 4; ++r) {
              int key = jt * 64 + nt * 16 + quad * 4 + r;
              if (key > q) s[mt][nt][r] = -3.0e38f;
            }
          }
      }
      bf16x4 pb[2][4];
#pragma unroll
      for (int mt = 0; mt < 2; ++mt) {
        // per-q max: in-register tree + 2 cross-lane xors (q = l16; quads hold different keys)
        f32x4 vm;
#pragma unroll
        for (int r = 0; r < 4; ++r)
          vm[r] = fmaxf(fmaxf(s[mt][0][r], s[mt][1][r]), fmaxf(s[mt][2][r], s[mt][3][r]));
        float mx = fmaxf(fmaxf(vm[0], vm[1]), fmaxf(vm[2], vm[3]));
        mx = fmaxf(mx, __shfl_xor(mx, 16));
        mx = fmaxf(mx, __shfl_xor(mx, 32));
        float nm = fmaxf(mst[mt], mx);
        float al = __builtin_amdgcn_exp2f(mst[mt] - nm);
        mst[mt] = nm;
        Lacc[mt] *= al;
#pragma unroll
        for (int dt = 0; dt < 8; ++dt) O[mt][dt] *= al;
        // P = exp2(S^T - m) -> bf16 B-fragments, directly in registers
#pragma unroll
        for (int nt = 0; nt < 4; ++nt) {
          bf16x4 p;
#pragma unroll
          for (int r = 0; r < 4; ++r) p[r] = f2bf(__builtin_amdgcn_exp2f(s[mt][nt][r] - nm));
          pb[mt][nt] = p;
        }
      }
      // O^T += V^T·P^T ; Lacc += 1·P^T   (16x16x16, k=16 keys per step)
#pragma unroll
      for (int nt = 0; nt < 4; ++nt) {
        int coff = ((nt * 2 + (quad >> 1)) ^ (l16 & 7)) * 8 + (quad & 1) * 4;
        bf16x4 av[8];
#pragma unroll
        for (int dt = 0; dt < 8; ++dt) av[dt] = *(const bf16x4*)&vs[cur][(dt * 16 + l16) * 64 + coff];
#pragma unroll
        for (int mt = 0; mt < 2; ++mt) {
#pragma unroll
          for (int dt = 0; dt < 8; ++dt)
            O[mt][dt] = __builtin_amdgcn_mfma_f32_16x16x16bf16_1k(av[dt], pb[mt][nt], O[mt][dt], 0, 0, 0);
          Lacc[mt] = __builtin_amdgcn_mfma_f32_16x16x16bf16_1k(ones4, pb[mt][nt], Lacc[mt], 0, 0, 0);
        }
      }
    }
    __syncthreads();
  }
#undef STAGE
  // epilogue: y[q][h*128+d] = O^T[d][q] / l[q]; lane writes 4 consecutive d per (mt,dt)
#pragma unroll
  for (int mt = 0; mt < 2; ++mt) {
    float inv = __builtin_amdgcn_rcpf(Lacc[mt][0]);
    int q = qt * 128 + w * 32 + mt * 16 + l16;
#pragma unroll
    for (int dt = 0; dt < 8; ++dt) {
      short4 s4;
      s4.x = f2bf(O[mt][dt][0] * inv);
      s4.y = f2bf(O[mt][dt][1] * inv);
      s4.z = f2bf(O[mt][dt][2] * inv);
      s4.w = f2bf(O[mt][dt][3] * inv);
      *(short4*)&y[((long)(b * 2048 + q)) * 2048 + h * 128 + dt * 16 + quad * 4] = s4;
    }
  }
}

extern "C" void kernel_launch(void* const* d_in, const int* in_sizes, int n_in,
                              void* d_out, int out_size, void* d_ws, size_t ws_size,
                              hipStream_t stream) {
  const float* x       = (const float*)d_in[0];
  const float* diag    = (const float*)d_in[1];
  const float* left_w  = (const float*)d_in[2];
  const float* right_w = (const float*)d_in[3];
  const float* right_b = (const float*)d_in[4];
  const float* bias_p  = (const float*)d_in[5];
  float* out = (float*)d_out;

  char* ws = (char*)d_ws;
  short* xb = (short*)(ws + 0);              // 33,554,432 B  (aliased as y after attention)
  short* LT = (short*)(ws + 33554432);       //  2,097,152 B
  short* WT = (short*)(ws + 35651584);       //  4,194,304 B
  short* xl = (short*)(ws + 39845888);       //  6,291,456 B
  short* yl = (short*)(ws + 46137344);       //  2,097,152 B
  short* qb = (short*)(ws + 48234496);       // 33,554,432 B
  short* kb = (short*)(ws + 81788928);       // 33,554,432 B
  short* vT = (short*)(ws + 115343360);      // 33,554,432 B
  short* y  = xb;

  cast_x_kernel<<<16384, 256, 0, stream>>>(x, xb, 4194304L);
  prep_kernel<<<12288, 256, 0, stream>>>(left_w, diag, right_w, LT, WT);
  gemm_bt<<<dim3(64, 3), 256, 0, stream>>>(xb, LT, xl, 8192, 384, 2048);
  lori_gemm<<<dim3(64, 48), 256, 0, stream>>>(xb, xl, 384, WT, right_b, bias_p, 0, qb, kb, vT, nullptr);
  attn_kernel<<<dim3(1024), 256, 0, stream>>>(qb, kb, vT, y);
  gemm_bt<<<dim3(64, 1), 256, 0, stream>>>(y, LT + 3L * 128 * 2048, yl, 8192, 128, 2048);
  lori_gemm<<<dim3(64, 16), 256, 0, stream>>>(y, yl, 128, WT, right_b, bias_p, 3, nullptr, nullptr, nullptr, out);
}

// Round 6
// 453.770 us; speedup vs baseline: 1.8565x; 1.1343x over previous
//
#include <hip/hip_runtime.h>

typedef short bf16x8 __attribute__((ext_vector_type(8)));
typedef short bf16x4 __attribute__((ext_vector_type(4)));
typedef float f32x4  __attribute__((ext_vector_type(4)));

#define AS1 __attribute__((address_space(1)))
#define AS3 __attribute__((address_space(3)))

__device__ __forceinline__ void gload16(const void* g, void* l) {
  __builtin_amdgcn_global_load_lds((const AS1 void*)g, (AS3 void*)l, 16, 0, 0);
}

__device__ __forceinline__ short f2bf(float f) {
  union { float fv; unsigned u; } v; v.fv = f;
  unsigned r = v.u + 0x7fffu + ((v.u >> 16) & 1u);
  return (short)(r >> 16);
}

// truncating f32->bf16 (P in (0,1]; numerator & denominator share P so bias cancels)
__device__ __forceinline__ short f2bf_t(float f) {
  return (short)(__float_as_uint(f) >> 16);
}

// ---------------- cast x (fp32 -> bf16), 4 elems/thread ----------------
__global__ void cast_x_kernel(const float* __restrict__ x, short* __restrict__ xb, long n4) {
  long i = (long)blockIdx.x * 256 + threadIdx.x;
  if (i < n4) {
    float4 v = ((const float4*)x)[i];
    short4 s;
    s.x = f2bf(v.x); s.y = f2bf(v.y); s.z = f2bf(v.z); s.w = f2bf(v.w);
    ((short4*)xb)[i] = s;
  }
}

// ---------------- weight prep ----------------
__global__ void prep_kernel(const float* __restrict__ left_w, const float* __restrict__ diag,
                            const float* __restrict__ right_w,
                            short* __restrict__ LT, short* __restrict__ WT) {
  long idx = (long)blockIdx.x * 256 + threadIdx.x;
  const long LTN = 4L * 128 * 2048;
  const long WTN = 4L * 16 * 128 * 256;
  if (idx < LTN) {
    LT[idx] = f2bf(left_w[idx]);
  } else if (idx < LTN + WTN) {
    long j = idx - LTN;
    int d = (int)(j & 255);
    long rest = j >> 8;
    int e = (int)(rest & 127);
    long gi = rest >> 7;
    int i = (int)(gi >> 4), n = (int)(gi & 15);
    float v;
    if (d < 128) v = diag[(gi * 128 + d) * 128 + e];
    else         v = right_w[((long)i * 2048 + n * 128 + e) * 128 + (d - 128)];
    WT[j] = f2bf(v);
  }
}

// ---------------- 128x128-tile GEMM (XOR-swizzled LDS): C = A @ BT^T ----------------
__global__ __launch_bounds__(256) void gemm_bt(const short* __restrict__ A, const short* __restrict__ BT,
                                               short* __restrict__ C, int M, int N, int K) {
  __shared__ __align__(16) short As[128 * 64];
  __shared__ __align__(16) short Bs[128 * 64];
  int tid = threadIdx.x, w = tid >> 6, lane = tid & 63;
  int m0 = blockIdx.x * 128, n0 = blockIdx.y * 128;
  int wm = (w >> 1) * 64, wn = (w & 1) * 64;
  int quad = lane >> 4, l16 = lane & 15;
  int srow = lane >> 3;
  int schunk = ((lane & 7) ^ srow) * 8;   // XOR-swizzled source chunk
  f32x4 acc[4][4] = {};
  for (int k0 = 0; k0 < K; k0 += 64) {
    for (int p = 0; p < 4; ++p) {
      int r = p * 32 + w * 8 + srow;
      gload16(&A[(long)(m0 + r) * K + k0 + schunk], &As[(p * 32 + w * 8) * 64]);
      gload16(&BT[(long)(n0 + r) * K + k0 + schunk], &Bs[(p * 32 + w * 8) * 64]);
    }
    __syncthreads();
#pragma unroll
    for (int kk = 0; kk < 2; ++kk) {
      int c = (((kk * 4 + quad) ^ (l16 & 7)) * 8);
      bf16x8 a[4], b[4];
#pragma unroll
      for (int t = 0; t < 4; ++t) a[t] = *(const bf16x8*)&As[(wm + t * 16 + l16) * 64 + c];
#pragma unroll
      for (int t = 0; t < 4; ++t) b[t] = *(const bf16x8*)&Bs[(wn + t * 16 + l16) * 64 + c];
#pragma unroll
      for (int mt = 0; mt < 4; ++mt)
#pragma unroll
        for (int nt = 0; nt < 4; ++nt)
          acc[mt][nt] = __builtin_amdgcn_mfma_f32_16x16x32_bf16(a[mt], b[nt], acc[mt][nt], 0, 0, 0);
    }
    __syncthreads();
  }
#pragma unroll
  for (int mt = 0; mt < 4; ++mt)
#pragma unroll
    for (int nt = 0; nt < 4; ++nt)
#pragma unroll
      for (int r = 0; r < 4; ++r) {
        int m = m0 + wm + mt * 16 + quad * 4 + r;
        int n = n0 + wn + nt * 16 + l16;
        C[(long)m * N + n] = f2bf(acc[mt][nt][r]);
      }
}

// ---------------- grouped lori GEMM (XOR-swizzled LDS) ----------------
__global__ __launch_bounds__(256) void lori_gemm(const short* __restrict__ tok, const short* __restrict__ rnk,
                                                 int rstride, const short* __restrict__ WT,
                                                 const float* __restrict__ rb, const float* __restrict__ bp,
                                                 int i_base, short* __restrict__ qb, short* __restrict__ kb,
                                                 short* __restrict__ vT, float* __restrict__ out) {
  __shared__ __align__(16) short As[128 * 64];
  __shared__ __align__(16) short Bs[128 * 64];
  int tid = threadIdx.x, w = tid >> 6, lane = tid & 63;
  int i = i_base + (blockIdx.y >> 4);
  int n = blockIdx.y & 15;
  int t0 = blockIdx.x * 128;
  int co = (i < 3) ? i * 128 : 0;
  const short* WTn = WT + (long)(i * 16 + n) * 128 * 256;
  int wm = (w >> 1) * 64, wn = (w & 1) * 64;
  int quad = lane >> 4, l16 = lane & 15;
  int srow = lane >> 3;
  int schunk = ((lane & 7) ^ srow) * 8;
  f32x4 acc[4][4] = {};
#pragma unroll
  for (int kt = 0; kt < 4; ++kt) {
    for (int p = 0; p < 4; ++p) {
      int r = p * 32 + w * 8 + srow;
      const short* ga;
      if (kt < 2) ga = &tok[(long)(t0 + r) * 2048 + n * 128 + kt * 64 + schunk];
      else        ga = &rnk[(long)(t0 + r) * rstride + co + (kt - 2) * 64 + schunk];
      gload16(ga, &As[(p * 32 + w * 8) * 64]);
      gload16(&WTn[r * 256 + kt * 64 + schunk], &Bs[(p * 32 + w * 8) * 64]);
    }
    __syncthreads();
#pragma unroll
    for (int kk = 0; kk < 2; ++kk) {
      int c = (((kk * 4 + quad) ^ (l16 & 7)) * 8);
      bf16x8 a[4], b[4];
#pragma unroll
      for (int t = 0; t < 4; ++t) a[t] = *(const bf16x8*)&As[(wm + t * 16 + l16) * 64 + c];
#pragma unroll
      for (int t = 0; t < 4; ++t) b[t] = *(const bf16x8*)&Bs[(wn + t * 16 + l16) * 64 + c];
#pragma unroll
      for (int mt = 0; mt < 4; ++mt)
#pragma unroll
        for (int nt = 0; nt < 4; ++nt)
          acc[mt][nt] = __builtin_amdgcn_mfma_f32_16x16x32_bf16(a[mt], b[nt], acc[mt][nt], 0, 0, 0);
    }
    __syncthreads();
  }
  int b = t0 >> 11;
  int tl0 = t0 & 2047;
  const float QSC = 0.08838834764831845f * 1.4426950408889634f;  // 1/sqrt(128) * log2(e)
#pragma unroll
  for (int mt = 0; mt < 4; ++mt) {
#pragma unroll
    for (int nt = 0; nt < 4; ++nt) {
      int e = wn + nt * 16 + l16;
      int c = n * 128 + e;
      float bias = rb[i * 2048 + c] + bp[i * 2048 + c];
      int tl = tl0 + wm + mt * 16 + quad * 4;
      if (i == 0) {
#pragma unroll
        for (int r = 0; r < 4; ++r)
          qb[((long)(b * 16 + n) * 2048 + tl + r) * 128 + e] = f2bf((acc[mt][nt][r] + bias) * QSC);
      } else if (i == 1) {
#pragma unroll
        for (int r = 0; r < 4; ++r)
          kb[((long)(b * 16 + n) * 2048 + tl + r) * 128 + e] = f2bf(acc[mt][nt][r] + bias);
      } else if (i == 2) {
        short4 s4;
        s4.x = f2bf(acc[mt][nt][0] + bias);
        s4.y = f2bf(acc[mt][nt][1] + bias);
        s4.z = f2bf(acc[mt][nt][2] + bias);
        s4.w = f2bf(acc[mt][nt][3] + bias);
        *(short4*)&vT[((long)(b * 16 + n) * 128 + e) * 2048 + tl] = s4;
      } else {
#pragma unroll
        for (int r = 0; r < 4; ++r)
          out[(long)(t0 + wm + mt * 16 + quad * 4 + r) * 2048 + c] = acc[mt][nt][r] + bias;
      }
    }
  }
}

// ---------------- flash attention v6: 512-thread blocks, 256-row q tile, S^T register-P ----------------
// qb,kb: [bh][t][d] bf16 (q pre-scaled by log2e/sqrt(128)); vT: [bh][d][t]; y: [b][t][h*128+d]
// grid: 512 blocks; id&7 = XCD; 8 bh per XCD; round 0 takes qt {7..4}, round 1 {3..0} (long+short per CU).
__global__ __launch_bounds__(512, 3) void attn_kernel(const short* __restrict__ qb, const short* __restrict__ kb,
                                                      const short* __restrict__ vT, short* __restrict__ y) {
  __shared__ __align__(16) short ks[2][64 * 128];   // K tiles, 16-chunk XOR swizzle per row
  __shared__ __align__(16) short vs[2][128 * 64];   // V^T tiles, 8-chunk XOR swizzle per row
  int tid = threadIdx.x, w = tid >> 6, lane = tid & 63;
  int id = blockIdx.x;
  int xcd = id & 7;
  int sl = (id >> 3) & 31;
  int round = id >> 8;
  int bh = xcd + 8 * (sl & 7);
  int qt = round ? (sl >> 3) : 7 - (sl >> 3);   // long q-tiles dispatched first
  int b = bh >> 4, h = bh & 15;
  int quad = lane >> 4, l16 = lane & 15;

  // Q fragments global->VGPR; serve as B-operand (k=d=quad*8+j, n=q=l16) of S^T MFMA
  bf16x8 aq[2][4];
#pragma unroll
  for (int mt = 0; mt < 2; ++mt)
#pragma unroll
    for (int kk = 0; kk < 4; ++kk)
      aq[mt][kk] = *(const bf16x8*)&qb[((long)bh * 2048 + qt * 256 + w * 32 + mt * 16 + l16) * 128 + kk * 32 + quad * 8];

  f32x4 O[2][8] = {};                 // O^T tiles: row=d (quad*4+r within dt), col=q (l16)
  f32x4 Lacc[2] = {};                 // ones-MFMA row-sum accumulator (rows identical)
  float mst[2] = {-3.0e38f, -3.0e38f};
  const bf16x4 ones4 = {(short)0x3F80, (short)0x3F80, (short)0x3F80, (short)0x3F80};

  // staging lane constants
  int kq = lane >> 4;
  int kchunk = l16 ^ ((w * 4 + kq) & 15);
  int vrow8 = lane >> 3;
  int vchunk = (lane & 7) ^ (vrow8 & 7);

  const short* kbase = kb + (long)bh * 2048 * 128;
  const short* vbase = vT + (long)bh * 128 * 2048;

#define STAGE(JT, BUF) {                                                              \
    for (int p = 0; p < 2; ++p) {                                                     \
      int r = p * 32 + w * 4 + kq;                                                    \
      gload16(&kbase[((long)((JT) * 64 + r)) * 128 + kchunk * 8], &ks[BUF][(p * 32 + w * 4) * 128]); \
      int r2 = p * 64 + w * 8 + vrow8;                                                \
      gload16(&vbase[(long)r2 * 2048 + (JT) * 64 + vchunk * 8], &vs[BUF][(p * 64 + w * 8) * 64]);    \
    }                                                                                 \
  }

  int jmax_w = 4 * qt + (w >> 1);     // wave's last (diagonal) key tile
  int jtend = 4 * qt + 3;             // block loop bound (uniform for barriers)
  STAGE(0, 0)
  __syncthreads();
  for (int jt = 0; jt <= jtend; ++jt) {
    int cur = jt & 1;
    if (jt < jtend) STAGE(jt + 1, cur ^ 1)   // prefetch overlaps compute below

    if (jt <= jmax_w) {
      // S^T = K·Q^T  (wave: 64 keys x 32 q)
      f32x4 s[2][4] = {};
#pragma unroll
      for (int nt = 0; nt < 4; ++nt)
#pragma unroll
        for (int kk = 0; kk < 4; ++kk) {
          bf16x8 bk = *(const bf16x8*)&ks[cur][(nt * 16 + l16) * 128 + (((kk * 4 + quad) ^ l16) * 8)];
          s[0][nt] = __builtin_amdgcn_mfma_f32_16x16x32_bf16(bk, aq[0][kk], s[0][nt], 0, 0, 0);
          s[1][nt] = __builtin_amdgcn_mfma_f32_16x16x32_bf16(bk, aq[1][kk], s[1][nt], 0, 0, 0);
        }
      if (jt == jmax_w) {   // diagonal tile: causal mask
#pragma unroll
        for (int mt = 0; mt < 2; ++mt)
#pragma unroll
          for (int nt = 0; nt < 4; ++nt) {
            int q = qt * 256 + w * 32 + mt * 16 + l16;
#pragma unroll
            for (int r = 0; r < 4; ++r) {
              int key = jt * 64 + nt * 16 + quad * 4 + r;
              if (key > q) s[mt][nt][r] = -3.0e38f;
            }
          }
      }
      bf16x4 pb[2][4];
#pragma unroll
      for (int mt = 0; mt < 2; ++mt) {
        // per-q max: in-register tree + 2 cross-lane xors (q = l16; quads hold different keys)
        f32x4 vm;
#pragma unroll
        for (int r = 0; r < 4; ++r)
          vm[r] = fmaxf(fmaxf(s[mt][0][r], s[mt][1][r]), fmaxf(s[mt][2][r], s[mt][3][r]));
        float mx = fmaxf(fmaxf(vm[0], vm[1]), fmaxf(vm[2], vm[3]));
        mx = fmaxf(mx, __shfl_xor(mx, 16));
        mx = fmaxf(mx, __shfl_xor(mx, 32));
        float nm = fmaxf(mst[mt], mx);
        float al = __builtin_amdgcn_exp2f(mst[mt] - nm);
        mst[mt] = nm;
        Lacc[mt] *= al;
#pragma unroll
        for (int dt = 0; dt < 8; ++dt) O[mt][dt] *= al;
        // P = exp2(S^T - m) -> bf16 B-fragments (truncating cvt), directly in registers
#pragma unroll
        for (int nt = 0; nt < 4; ++nt) {
          bf16x4 p;
#pragma unroll
          for (int r = 0; r < 4; ++r) p[r] = f2bf_t(__builtin_amdgcn_exp2f(s[mt][nt][r] - nm));
          pb[mt][nt] = p;
        }
      }
      // O^T += V^T·P^T ; Lacc += 1·P^T   (16x16x16, k=16 keys per step)
#pragma unroll
      for (int nt = 0; nt < 4; ++nt) {
        int coff = ((nt * 2 + (quad >> 1)) ^ (l16 & 7)) * 8 + (quad & 1) * 4;
        bf16x4 av[8];
#pragma unroll
        for (int dt = 0; dt < 8; ++dt) av[dt] = *(const bf16x4*)&vs[cur][(dt * 16 + l16) * 64 + coff];
#pragma unroll
        for (int mt = 0; mt < 2; ++mt) {
#pragma unroll
          for (int dt = 0; dt < 8; ++dt)
            O[mt][dt] = __builtin_amdgcn_mfma_f32_16x16x16bf16_1k(av[dt], pb[mt][nt], O[mt][dt], 0, 0, 0);
          Lacc[mt] = __builtin_amdgcn_mfma_f32_16x16x16bf16_1k(ones4, pb[mt][nt], Lacc[mt], 0, 0, 0);
        }
      }
    }
    __syncthreads();
  }
#undef STAGE
  // epilogue: y[q][h*128+d] = O^T[d][q] / l[q]; lane writes 4 consecutive d per (mt,dt)
#pragma unroll
  for (int mt = 0; mt < 2; ++mt) {
    float inv = __builtin_amdgcn_rcpf(Lacc[mt][0]);
    int q = qt * 256 + w * 32 + mt * 16 + l16;
#pragma unroll
    for (int dt = 0; dt < 8; ++dt) {
      short4 s4;
      s4.x = f2bf(O[mt][dt][0] * inv);
      s4.y = f2bf(O[mt][dt][1] * inv);
      s4.z = f2bf(O[mt][dt][2] * inv);
      s4.w = f2bf(O[mt][dt][3] * inv);
      *(short4*)&y[((long)(b * 2048 + q)) * 2048 + h * 128 + dt * 16 + quad * 4] = s4;
    }
  }
}

extern "C" void kernel_launch(void* const* d_in, const int* in_sizes, int n_in,
                              void* d_out, int out_size, void* d_ws, size_t ws_size,
                              hipStream_t stream) {
  const float* x       = (const float*)d_in[0];
  const float* diag    = (const float*)d_in[1];
  const float* left_w  = (const float*)d_in[2];
  const float* right_w = (const float*)d_in[3];
  const float* right_b = (const float*)d_in[4];
  const float* bias_p  = (const float*)d_in[5];
  float* out = (float*)d_out;

  char* ws = (char*)d_ws;
  short* xb = (short*)(ws + 0);              // 33,554,432 B  (aliased as y after attention)
  short* LT = (short*)(ws + 33554432);       //  2,097,152 B
  short* WT = (short*)(ws + 35651584);       //  4,194,304 B
  short* xl = (short*)(ws + 39845888);       //  6,291,456 B
  short* yl = (short*)(ws + 46137344);       //  2,097,152 B
  short* qb = (short*)(ws + 48234496);       // 33,554,432 B
  short* kb = (short*)(ws + 81788928);       // 33,554,432 B
  short* vT = (short*)(ws + 115343360);      // 33,554,432 B
  short* y  = xb;

  cast_x_kernel<<<16384, 256, 0, stream>>>(x, xb, 4194304L);
  prep_kernel<<<12288, 256, 0, stream>>>(left_w, diag, right_w, LT, WT);
  gemm_bt<<<dim3(64, 3), 256, 0, stream>>>(xb, LT, xl, 8192, 384, 2048);
  lori_gemm<<<dim3(64, 48), 256, 0, stream>>>(xb, xl, 384, WT, right_b, bias_p, 0, qb, kb, vT, nullptr);
  attn_kernel<<<dim3(512), 512, 0, stream>>>(qb, kb, vT, y);
  gemm_bt<<<dim3(64, 1), 256, 0, stream>>>(y, LT + 3L * 128 * 2048, yl, 8192, 128, 2048);
  lori_gemm<<<dim3(64, 16), 256, 0, stream>>>(y, yl, 128, WT, right_b, bias_p, 3, nullptr, nullptr, nullptr, out);
}

// Round 7
// 437.417 us; speedup vs baseline: 1.9259x; 1.0374x over previous
//
#include <hip/hip_runtime.h>

typedef short bf16x8 __attribute__((ext_vector_type(8)));
typedef short bf16x4 __attribute__((ext_vector_type(4)));
typedef float f32x4  __attribute__((ext_vector_type(4)));

#define AS1 __attribute__((address_space(1)))
#define AS3 __attribute__((address_space(3)))

__device__ __forceinline__ void gload16(const void* g, void* l) {
  __builtin_amdgcn_global_load_lds((const AS1 void*)g, (AS3 void*)l, 16, 0, 0);
}

__device__ __forceinline__ short f2bf(float f) {
  union { float fv; unsigned u; } v; v.fv = f;
  unsigned r = v.u + 0x7fffu + ((v.u >> 16) & 1u);
  return (short)(r >> 16);
}

// truncating f32->bf16 (P in (0,1]; numerator & denominator share P so bias cancels)
__device__ __forceinline__ short f2bf_t(float f) {
  return (short)(__float_as_uint(f) >> 16);
}

// ---------------- fused cast x (fp32->bf16, float4/thread) + weight prep ----------------
__global__ void cast_prep_kernel(const float* __restrict__ x, const float* __restrict__ left_w,
                                 const float* __restrict__ diag, const float* __restrict__ right_w,
                                 short* __restrict__ xb, short* __restrict__ LT, short* __restrict__ WT) {
  long idx = (long)blockIdx.x * 256 + threadIdx.x;
  const long N4 = 4194304L;              // x elements / 4
  const long LTN = 4L * 128 * 2048;
  const long WTN = 4L * 16 * 128 * 256;
  if (idx < N4) {
    float4 v = ((const float4*)x)[idx];
    short4 s;
    s.x = f2bf(v.x); s.y = f2bf(v.y); s.z = f2bf(v.z); s.w = f2bf(v.w);
    ((short4*)xb)[idx] = s;
  } else if (idx < N4 + LTN) {
    long j = idx - N4;
    LT[j] = f2bf(left_w[j]);
  } else if (idx < N4 + LTN + WTN) {
    long j = idx - N4 - LTN;
    int d = (int)(j & 255);
    long rest = j >> 8;
    int e = (int)(rest & 127);
    long gi = rest >> 7;
    int i = (int)(gi >> 4), n = (int)(gi & 15);
    float v;
    if (d < 128) v = diag[(gi * 128 + d) * 128 + e];
    else         v = right_w[((long)i * 2048 + n * 128 + e) * 128 + (d - 128)];
    WT[j] = f2bf(v);
  }
}

// ---------------- 128x128-tile GEMM, double-buffered K (XOR-swizzled LDS): C = A @ BT^T ----------------
__global__ __launch_bounds__(256) void gemm_bt(const short* __restrict__ A, const short* __restrict__ BT,
                                               short* __restrict__ C, int M, int N, int K) {
  __shared__ __align__(16) short As[2][128 * 64];
  __shared__ __align__(16) short Bs[2][128 * 64];
  int tid = threadIdx.x, w = tid >> 6, lane = tid & 63;
  int m0 = blockIdx.x * 128, n0 = blockIdx.y * 128;
  int wm = (w >> 1) * 64, wn = (w & 1) * 64;
  int quad = lane >> 4, l16 = lane & 15;
  int srow = lane >> 3;
  int schunk = ((lane & 7) ^ srow) * 8;   // XOR-swizzled source chunk

#define GSTAGE(K0, BUF) {                                                             \
    for (int p = 0; p < 4; ++p) {                                                     \
      int r = p * 32 + w * 8 + srow;                                                  \
      gload16(&A[(long)(m0 + r) * K + (K0) + schunk], &As[BUF][(p * 32 + w * 8) * 64]); \
      gload16(&BT[(long)(n0 + r) * K + (K0) + schunk], &Bs[BUF][(p * 32 + w * 8) * 64]); \
    }                                                                                 \
  }

  f32x4 acc[4][4] = {};
  GSTAGE(0, 0)
  __syncthreads();
  int nk = K >> 6;
  for (int it = 0; it < nk; ++it) {
    int cur = it & 1;
    if (it + 1 < nk) GSTAGE((it + 1) * 64, cur ^ 1)   // prefetch overlaps compute
#pragma unroll
    for (int kk = 0; kk < 2; ++kk) {
      int c = (((kk * 4 + quad) ^ (l16 & 7)) * 8);
      bf16x8 a[4], b[4];
#pragma unroll
      for (int t = 0; t < 4; ++t) a[t] = *(const bf16x8*)&As[cur][(wm + t * 16 + l16) * 64 + c];
#pragma unroll
      for (int t = 0; t < 4; ++t) b[t] = *(const bf16x8*)&Bs[cur][(wn + t * 16 + l16) * 64 + c];
#pragma unroll
      for (int mt = 0; mt < 4; ++mt)
#pragma unroll
        for (int nt = 0; nt < 4; ++nt)
          acc[mt][nt] = __builtin_amdgcn_mfma_f32_16x16x32_bf16(a[mt], b[nt], acc[mt][nt], 0, 0, 0);
    }
    __syncthreads();
  }
#undef GSTAGE
#pragma unroll
  for (int mt = 0; mt < 4; ++mt)
#pragma unroll
    for (int nt = 0; nt < 4; ++nt)
#pragma unroll
      for (int r = 0; r < 4; ++r) {
        int m = m0 + wm + mt * 16 + quad * 4 + r;
        int n = n0 + wn + nt * 16 + l16;
        C[(long)m * N + n] = f2bf(acc[mt][nt][r]);
      }
}

// ---------------- grouped lori GEMM, double-buffered kt (XOR-swizzled LDS) ----------------
__global__ __launch_bounds__(256) void lori_gemm(const short* __restrict__ tok, const short* __restrict__ rnk,
                                                 int rstride, const short* __restrict__ WT,
                                                 const float* __restrict__ rb, const float* __restrict__ bp,
                                                 int i_base, short* __restrict__ qb, short* __restrict__ kb,
                                                 short* __restrict__ vT, float* __restrict__ out) {
  __shared__ __align__(16) short As[2][128 * 64];
  __shared__ __align__(16) short Bs[2][128 * 64];
  int tid = threadIdx.x, w = tid >> 6, lane = tid & 63;
  int i = i_base + (blockIdx.y >> 4);
  int n = blockIdx.y & 15;
  int t0 = blockIdx.x * 128;
  int co = (i < 3) ? i * 128 : 0;
  const short* WTn = WT + (long)(i * 16 + n) * 128 * 256;
  int wm = (w >> 1) * 64, wn = (w & 1) * 64;
  int quad = lane >> 4, l16 = lane & 15;
  int srow = lane >> 3;
  int schunk = ((lane & 7) ^ srow) * 8;

#define LSTAGE(KT, BUF) {                                                             \
    for (int p = 0; p < 4; ++p) {                                                     \
      int r = p * 32 + w * 8 + srow;                                                  \
      const short* ga;                                                                \
      if ((KT) < 2) ga = &tok[(long)(t0 + r) * 2048 + n * 128 + (KT) * 64 + schunk];  \
      else          ga = &rnk[(long)(t0 + r) * rstride + co + ((KT) - 2) * 64 + schunk]; \
      gload16(ga, &As[BUF][(p * 32 + w * 8) * 64]);                                   \
      gload16(&WTn[r * 256 + (KT) * 64 + schunk], &Bs[BUF][(p * 32 + w * 8) * 64]);   \
    }                                                                                 \
  }

  f32x4 acc[4][4] = {};
  LSTAGE(0, 0)
  __syncthreads();
#pragma unroll
  for (int kt = 0; kt < 4; ++kt) {
    int cur = kt & 1;
    if (kt < 3) LSTAGE(kt + 1, cur ^ 1)   // prefetch overlaps compute
#pragma unroll
    for (int kk = 0; kk < 2; ++kk) {
      int c = (((kk * 4 + quad) ^ (l16 & 7)) * 8);
      bf16x8 a[4], b[4];
#pragma unroll
      for (int t = 0; t < 4; ++t) a[t] = *(const bf16x8*)&As[cur][(wm + t * 16 + l16) * 64 + c];
#pragma unroll
      for (int t = 0; t < 4; ++t) b[t] = *(const bf16x8*)&Bs[cur][(wn + t * 16 + l16) * 64 + c];
#pragma unroll
      for (int mt = 0; mt < 4; ++mt)
#pragma unroll
        for (int nt = 0; nt < 4; ++nt)
          acc[mt][nt] = __builtin_amdgcn_mfma_f32_16x16x32_bf16(a[mt], b[nt], acc[mt][nt], 0, 0, 0);
    }
    __syncthreads();
  }
#undef LSTAGE
  int b = t0 >> 11;
  int tl0 = t0 & 2047;
  const float QSC = 0.08838834764831845f * 1.4426950408889634f;  // 1/sqrt(128) * log2(e)
#pragma unroll
  for (int mt = 0; mt < 4; ++mt) {
#pragma unroll
    for (int nt = 0; nt < 4; ++nt) {
      int e = wn + nt * 16 + l16;
      int c = n * 128 + e;
      float bias = rb[i * 2048 + c] + bp[i * 2048 + c];
      int tl = tl0 + wm + mt * 16 + quad * 4;
      if (i == 0) {
#pragma unroll
        for (int r = 0; r < 4; ++r)
          qb[((long)(b * 16 + n) * 2048 + tl + r) * 128 + e] = f2bf((acc[mt][nt][r] + bias) * QSC);
      } else if (i == 1) {
#pragma unroll
        for (int r = 0; r < 4; ++r)
          kb[((long)(b * 16 + n) * 2048 + tl + r) * 128 + e] = f2bf(acc[mt][nt][r] + bias);
      } else if (i == 2) {
        short4 s4;
        s4.x = f2bf(acc[mt][nt][0] + bias);
        s4.y = f2bf(acc[mt][nt][1] + bias);
        s4.z = f2bf(acc[mt][nt][2] + bias);
        s4.w = f2bf(acc[mt][nt][3] + bias);
        *(short4*)&vT[((long)(b * 16 + n) * 128 + e) * 2048 + tl] = s4;
      } else {
#pragma unroll
        for (int r = 0; r < 4; ++r)
          out[(long)(t0 + wm + mt * 16 + quad * 4 + r) * 2048 + c] = acc[mt][nt][r] + bias;
      }
    }
  }
}

// ---------------- flash attention v6: 512-thread blocks, 256-row q tile, S^T register-P ----------------
// qb,kb: [bh][t][d] bf16 (q pre-scaled by log2e/sqrt(128)); vT: [bh][d][t]; y: [b][t][h*128+d]
// grid: 512 blocks; id&7 = XCD; 8 bh per XCD; round 0 takes qt {7..4}, round 1 {3..0} (long+short per CU).
__global__ __launch_bounds__(512, 3) void attn_kernel(const short* __restrict__ qb, const short* __restrict__ kb,
                                                      const short* __restrict__ vT, short* __restrict__ y) {
  __shared__ __align__(16) short ks[2][64 * 128];   // K tiles, 16-chunk XOR swizzle per row
  __shared__ __align__(16) short vs[2][128 * 64];   // V^T tiles, 8-chunk XOR swizzle per row
  int tid = threadIdx.x, w = tid >> 6, lane = tid & 63;
  int id = blockIdx.x;
  int xcd = id & 7;
  int sl = (id >> 3) & 31;
  int round = id >> 8;
  int bh = xcd + 8 * (sl & 7);
  int qt = round ? (sl >> 3) : 7 - (sl >> 3);   // long q-tiles dispatched first
  int b = bh >> 4, h = bh & 15;
  int quad = lane >> 4, l16 = lane & 15;

  // Q fragments global->VGPR; serve as B-operand (k=d=quad*8+j, n=q=l16) of S^T MFMA
  bf16x8 aq[2][4];
#pragma unroll
  for (int mt = 0; mt < 2; ++mt)
#pragma unroll
    for (int kk = 0; kk < 4; ++kk)
      aq[mt][kk] = *(const bf16x8*)&qb[((long)bh * 2048 + qt * 256 + w * 32 + mt * 16 + l16) * 128 + kk * 32 + quad * 8];

  f32x4 O[2][8] = {};                 // O^T tiles: row=d (quad*4+r within dt), col=q (l16)
  f32x4 Lacc[2] = {};                 // ones-MFMA row-sum accumulator (rows identical)
  float mst[2] = {-3.0e38f, -3.0e38f};
  const bf16x4 ones4 = {(short)0x3F80, (short)0x3F80, (short)0x3F80, (short)0x3F80};

  // staging lane constants
  int kq = lane >> 4;
  int kchunk = l16 ^ ((w * 4 + kq) & 15);
  int vrow8 = lane >> 3;
  int vchunk = (lane & 7) ^ (vrow8 & 7);

  const short* kbase = kb + (long)bh * 2048 * 128;
  const short* vbase = vT + (long)bh * 128 * 2048;

#define STAGE(JT, BUF) {                                                              \
    for (int p = 0; p < 2; ++p) {                                                     \
      int r = p * 32 + w * 4 + kq;                                                    \
      gload16(&kbase[((long)((JT) * 64 + r)) * 128 + kchunk * 8], &ks[BUF][(p * 32 + w * 4) * 128]); \
      int r2 = p * 64 + w * 8 + vrow8;                                                \
      gload16(&vbase[(long)r2 * 2048 + (JT) * 64 + vchunk * 8], &vs[BUF][(p * 64 + w * 8) * 64]);    \
    }                                                                                 \
  }

  int jmax_w = 4 * qt + (w >> 1);     // wave's last (diagonal) key tile
  int jtend = 4 * qt + 3;             // block loop bound (uniform for barriers)
  STAGE(0, 0)
  __syncthreads();
  for (int jt = 0; jt <= jtend; ++jt) {
    int cur = jt & 1;
    if (jt < jtend) STAGE(jt + 1, cur ^ 1)   // prefetch overlaps compute below

    if (jt <= jmax_w) {
      // S^T = K·Q^T  (wave: 64 keys x 32 q)
      f32x4 s[2][4] = {};
#pragma unroll
      for (int nt = 0; nt < 4; ++nt)
#pragma unroll
        for (int kk = 0; kk < 4; ++kk) {
          bf16x8 bk = *(const bf16x8*)&ks[cur][(nt * 16 + l16) * 128 + (((kk * 4 + quad) ^ l16) * 8)];
          s[0][nt] = __builtin_amdgcn_mfma_f32_16x16x32_bf16(bk, aq[0][kk], s[0][nt], 0, 0, 0);
          s[1][nt] = __builtin_amdgcn_mfma_f32_16x16x32_bf16(bk, aq[1][kk], s[1][nt], 0, 0, 0);
        }
      if (jt == jmax_w) {   // diagonal tile: causal mask
#pragma unroll
        for (int mt = 0; mt < 2; ++mt)
#pragma unroll
          for (int nt = 0; nt < 4; ++nt) {
            int q = qt * 256 + w * 32 + mt * 16 + l16;
#pragma unroll
            for (int r = 0; r < 4; ++r) {
              int key = jt * 64 + nt * 16 + quad * 4 + r;
              if (key > q) s[mt][nt][r] = -3.0e38f;
            }
          }
      }
      bf16x4 pb[2][4];
#pragma unroll
      for (int mt = 0; mt < 2; ++mt) {
        // per-q max: in-register tree + 2 cross-lane xors (q = l16; quads hold different keys)
        f32x4 vm;
#pragma unroll
        for (int r = 0; r < 4; ++r)
          vm[r] = fmaxf(fmaxf(s[mt][0][r], s[mt][1][r]), fmaxf(s[mt][2][r], s[mt][3][r]));
        float mx = fmaxf(fmaxf(vm[0], vm[1]), fmaxf(vm[2], vm[3]));
        mx = fmaxf(mx, __shfl_xor(mx, 16));
        mx = fmaxf(mx, __shfl_xor(mx, 32));
        float nm = fmaxf(mst[mt], mx);
        float al = __builtin_amdgcn_exp2f(mst[mt] - nm);
        mst[mt] = nm;
        Lacc[mt] *= al;
#pragma unroll
        for (int dt = 0; dt < 8; ++dt) O[mt][dt] *= al;
        // P = exp2(S^T - m) -> bf16 B-fragments (truncating cvt), directly in registers
#pragma unroll
        for (int nt = 0; nt < 4; ++nt) {
          bf16x4 p;
#pragma unroll
          for (int r = 0; r < 4; ++r) p[r] = f2bf_t(__builtin_amdgcn_exp2f(s[mt][nt][r] - nm));
          pb[mt][nt] = p;
        }
      }
      // O^T += V^T·P^T ; Lacc += 1·P^T   (16x16x16, k=16 keys per step)
#pragma unroll
      for (int nt = 0; nt < 4; ++nt) {
        int coff = ((nt * 2 + (quad >> 1)) ^ (l16 & 7)) * 8 + (quad & 1) * 4;
        bf16x4 av[8];
#pragma unroll
        for (int dt = 0; dt < 8; ++dt) av[dt] = *(const bf16x4*)&vs[cur][(dt * 16 + l16) * 64 + coff];
#pragma unroll
        for (int mt = 0; mt < 2; ++mt) {
#pragma unroll
          for (int dt = 0; dt < 8; ++dt)
            O[mt][dt] = __builtin_amdgcn_mfma_f32_16x16x16bf16_1k(av[dt], pb[mt][nt], O[mt][dt], 0, 0, 0);
          Lacc[mt] = __builtin_amdgcn_mfma_f32_16x16x16bf16_1k(ones4, pb[mt][nt], Lacc[mt], 0, 0, 0);
        }
      }
    }
    __syncthreads();
  }
#undef STAGE
  // epilogue: y[q][h*128+d] = O^T[d][q] / l[q]; lane writes 4 consecutive d per (mt,dt)
#pragma unroll
  for (int mt = 0; mt < 2; ++mt) {
    float inv = __builtin_amdgcn_rcpf(Lacc[mt][0]);
    int q = qt * 256 + w * 32 + mt * 16 + l16;
#pragma unroll
    for (int dt = 0; dt < 8; ++dt) {
      short4 s4;
      s4.x = f2bf(O[mt][dt][0] * inv);
      s4.y = f2bf(O[mt][dt][1] * inv);
      s4.z = f2bf(O[mt][dt][2] * inv);
      s4.w = f2bf(O[mt][dt][3] * inv);
      *(short4*)&y[((long)(b * 2048 + q)) * 2048 + h * 128 + dt * 16 + quad * 4] = s4;
    }
  }
}

extern "C" void kernel_launch(void* const* d_in, const int* in_sizes, int n_in,
                              void* d_out, int out_size, void* d_ws, size_t ws_size,
                              hipStream_t stream) {
  const float* x       = (const float*)d_in[0];
  const float* diag    = (const float*)d_in[1];
  const float* left_w  = (const float*)d_in[2];
  const float* right_w = (const float*)d_in[3];
  const float* right_b = (const float*)d_in[4];
  const float* bias_p  = (const float*)d_in[5];
  float* out = (float*)d_out;

  char* ws = (char*)d_ws;
  short* xb = (short*)(ws + 0);              // 33,554,432 B  (aliased as y after attention)
  short* LT = (short*)(ws + 33554432);       //  2,097,152 B
  short* WT = (short*)(ws + 35651584);       //  4,194,304 B
  short* xl = (short*)(ws + 39845888);       //  6,291,456 B
  short* yl = (short*)(ws + 46137344);       //  2,097,152 B
  short* qb = (short*)(ws + 48234496);       // 33,554,432 B
  short* kb = (short*)(ws + 81788928);       // 33,554,432 B
  short* vT = (short*)(ws + 115343360);      // 33,554,432 B
  short* y  = xb;

  cast_prep_kernel<<<28672, 256, 0, stream>>>(x, left_w, diag, right_w, xb, LT, WT);
  gemm_bt<<<dim3(64, 3), 256, 0, stream>>>(xb, LT, xl, 8192, 384, 2048);
  lori_gemm<<<dim3(64, 48), 256, 0, stream>>>(xb, xl, 384, WT, right_b, bias_p, 0, qb, kb, vT, nullptr);
  attn_kernel<<<dim3(512), 512, 0, stream>>>(qb, kb, vT, y);
  gemm_bt<<<dim3(64, 1), 256, 0, stream>>>(y, LT + 3L * 128 * 2048, yl, 8192, 128, 2048);
  lori_gemm<<<dim3(64, 16), 256, 0, stream>>>(y, yl, 128, WT, right_b, bias_p, 3, nullptr, nullptr, nullptr, out);
}